// Round 5
// baseline (745.123 us; speedup 1.0000x reference)
//
#include <hip/hip_runtime.h>

typedef _Float16 f16;
typedef _Float16 f16x4 __attribute__((ext_vector_type(4)));
typedef _Float16 f16x8 __attribute__((ext_vector_type(8)));
typedef float    f32x4 __attribute__((ext_vector_type(4)));

// ws layout (bytes)
#define OFF_WHP   0u          // f16 [5][16nt][8kk][64lane][8e]   = 655360 B
#define OFF_WLP   655360u     // f16 [8kk][64lane][8e]            = 8192 B
#define OFF_W0P   663552u     // f32 [8kk][64lane][8e][4i]        = 65536 B
#define OFF_B0P   729088u     // f32 [8kk][64lane][8e]            = 16384 B
#define OFF_GP    745472u     // f32 [3j][8kk][64lane][8e]        = 49152 B
#define OFF_BHP   794624u     // f32 [5l][16nt][64lane][4r]       = 81920 B

// k-slot map: slot (kk, lane-group g, elem e) -> k = (2kk+(e>>2))*16+4g+(e&3).
// Applied identically to A (weights, prepacked) and B (activations), so the
// MFMA D-output (n = nt*16+4g+r) lands exactly in next layer's B-slot
// (kk'=nt>>1, e'=(nt&1)*4+r): lane-local layer transitions.
__device__ __forceinline__ int phi(int kk, int g, int e){
  return (kk*2 + (e>>2))*16 + g*4 + (e&3);
}

__device__ __forceinline__ float tanh_fast(float z){
  float e = __builtin_amdgcn_exp2f(z * 2.885390081777927f);
  return 1.f - 2.f*__builtin_amdgcn_rcpf(e + 1.f);
}

__global__ void prepack(const float* __restrict__ W0, const float* __restrict__ b0,
                        const float* __restrict__ Wh, const float* __restrict__ bh,
                        const float* __restrict__ Wl, unsigned char* __restrict__ ws){
  int tid = blockIdx.x*256 + threadIdx.x;
  f16*   whp = (f16*)(ws + OFF_WHP);
  f16*   wlp = (f16*)(ws + OFF_WLP);
  float* w0p = (float*)(ws + OFF_W0P);
  float* b0p = (float*)(ws + OFF_B0P);
  float* gp  = (float*)(ws + OFF_GP);
  float* bhp = (float*)(ws + OFF_BHP);
  if (tid < 327680){                      // Wh fragments, f16
    int e=tid&7, lane=(tid>>3)&63, kk=(tid>>9)&7, nt=(tid>>12)&15, l=tid>>16;
    int k = phi(kk, lane>>4, e);
    int n = nt*16 + (lane&15);
    whp[tid] = (f16)Wh[(l*256 + k)*256 + n];
  } else if (tid < 331776){               // Wl fragments (N padded 3->16), f16
    int t = tid - 327680;
    int e=t&7, lane=(t>>3)&63, kk=t>>9;
    int k = phi(kk, lane>>4, e);
    int n = lane&15;
    wlp[t] = (n<3) ? (f16)Wl[k*3+n] : (f16)0.f;
  } else if (tid < 335872){               // W0 columns + b0 in slot order, f32
    int t = tid - 331776;
    int e=t&7, lane=(t>>3)&63, kk=t>>9;
    int k = phi(kk, lane>>4, e);
    #pragma unroll
    for(int i=0;i<4;i++) w0p[t*4+i] = W0[i*256+k];
    b0p[t] = b0[k];
  } else if (tid < 348160){               // g_j = W0[j,:] @ Wh[0], slot order, f32
    int t = tid - 335872;
    int e=t&7, lane=(t>>3)&63, kk=(t>>9)&7, j=t>>12;
    int k = phi(kk, lane>>4, e);
    float acc = 0.f;
    for(int k0=0;k0<256;k0++) acc = fmaf(W0[j*256+k0], Wh[k0*256+k], acc);
    gp[t] = acc;
  } else if (tid < 368640){               // bh in D-layout order, f32
    int t = tid - 348160;
    int r=t&3, lane=(t>>2)&63, nt=(t>>8)&15, l=t>>12;
    bhp[t] = bh[l*256 + nt*16 + (lane>>4)*4 + r];
  }
}

// R5: lane-local mask layout. Writer lane (s,g) of wave0 produces exactly the
// mask set reader lane (s,g) of waves 1..3 needs (n = nt*16+4g+r both sides),
// so masks live at [lane][chunk kk] f16x8, chunk XOR-swizzled across banks.
// One ds_read_b128 per kk replaces 2 b64 reads + shuffle (R4: 3.27M conflicts).
__device__ __forceinline__ int moff(int lane, int kk){
  return lane*128 + ((kk ^ (lane & 7)) << 4);
}

// Comp-per-wave decomposition: wave 0 = primal chain (publishes tanh' masks),
// waves 1..3 = one tangent chain each. Per-wave state ~64 VGPR -> no spill.
__global__ __launch_bounds__(256, 4) void velcurl(
    const float* __restrict__ x, const unsigned char* __restrict__ ws,
    float* __restrict__ out){
  __shared__ __align__(16) char mbuf[2][8192];   // masks, double-buffered
  __shared__ float outt[3][3][16];               // [j][n][s] final Jacobian rows

  const int lane  = threadIdx.x & 63;
  const int w     = threadIdx.x >> 6;   // 0 = primal, 1..3 = tangent j=w-1
  const int s     = lane & 15;          // sample column
  const int sbase = blockIdx.x << 4;    // 16 samples per block

  const f16x8* __restrict__ whp = (const f16x8*)(ws + OFF_WHP);
  const f16x8* __restrict__ wlp = (const f16x8*)(ws + OFF_WLP);
  const f32x4* __restrict__ w0p = (const f32x4*)(ws + OFF_W0P);
  const float* __restrict__ b0p = (const float*)(ws + OFF_B0P);
  const float* __restrict__ gp  = (const float*)(ws + OFF_GP);
  const f32x4* __restrict__ bhp = (const f32x4*)(ws + OFF_BHP);

  f16x8 st[8];    // primal: current h frags (B-slot order)
  f16x8 nst[8];   // next-state (primal h / unmasked tangent preact)

  // ---- phase 0: primal layer0 + Wh0, masks0 -> mbuf[0] ----
  if (w==0){
    const f32x4 xv = ((const f32x4*)x)[sbase + s];
    #pragma unroll
    for(int kk=0;kk<8;kk++){
      f16x8 v;
      #pragma unroll
      for(int e=0;e<8;e++){
        f32x4 wv = w0p[(kk*64+lane)*8+e];
        float b  = b0p[(kk*64+lane)*8+e];
        float h = fmaf(xv[3],wv[3], fmaf(xv[2],wv[2], fmaf(xv[1],wv[1], fmaf(xv[0],wv[0], b))));
        v[e] = (f16)h;
      }
      st[kk] = v;
    }
    f16x8 mc;
    #pragma unroll
    for(int nt=0;nt<16;nt++){
      f32x4 acc = {0.f,0.f,0.f,0.f};
      #pragma unroll
      for(int kk=0;kk<8;kk++)
        acc = __builtin_amdgcn_mfma_f32_16x16x32_f16(whp[(nt*8+kk)*64+lane], st[kk], acc, 0,0,0);
      f32x4 bv = bhp[nt*64+lane];
      #pragma unroll
      for(int r=0;r<4;r++){
        float h = tanh_fast(acc[r]+bv[r]);
        nst[nt>>1][(nt&1)*4+r] = (f16)h;
        mc[(nt&1)*4+r] = (f16)(1.f - h*h);
      }
      if (nt&1) *(f16x8*)(&mbuf[0][0] + moff(lane, nt>>1)) = mc;
    }
    #pragma unroll
    for(int kk=0;kk<8;kk++) st[kk]=nst[kk];
  }
  __syncthreads();

  // ---- phases 1..4: primal layer p || tangent layer p (uses masks p-1) ----
  #pragma unroll 1
  for(int p=1;p<5;p++){
    const f16x8* wl = whp + p*8192;
    if (w==0){
      const f32x4* bp = bhp + p*1024;
      char* mb = &mbuf[p&1][0];
      f16x8 mc;
      #pragma unroll
      for(int nt=0;nt<16;nt++){
        f32x4 acc = {0.f,0.f,0.f,0.f};
        #pragma unroll
        for(int kk=0;kk<8;kk++)
          acc = __builtin_amdgcn_mfma_f32_16x16x32_f16(wl[(nt*8+kk)*64+lane], st[kk], acc, 0,0,0);
        f32x4 bv = bp[nt*64+lane];
        #pragma unroll
        for(int r=0;r<4;r++){
          float h = tanh_fast(acc[r]+bv[r]);
          nst[nt>>1][(nt&1)*4+r] = (f16)h;
          mc[(nt&1)*4+r] = (f16)(1.f - h*h);
        }
        if (nt&1) *(f16x8*)(mb + moff(lane, nt>>1)) = mc;
      }
      #pragma unroll
      for(int kk=0;kk<8;kk++) st[kk]=nst[kk];
    } else {
      const char* mb = &mbuf[(p-1)&1][0];
      f16x8 bf[8];
      if (p==1){
        const int j = w-1;
        #pragma unroll
        for(int kk=0;kk<8;kk++){
          f16x8 m8 = *(const f16x8*)(mb + moff(lane, kk));
          f16x8 v;
          #pragma unroll
          for(int e=0;e<8;e++)
            v[e] = (f16)((float)m8[e] * gp[((j*8+kk)*64+lane)*8 + e]);
          bf[kk] = v;
        }
      } else {
        #pragma unroll
        for(int kk=0;kk<8;kk++){
          f16x8 m8 = *(const f16x8*)(mb + moff(lane, kk));
          bf[kk] = m8 * nst[kk];
        }
      }
      #pragma unroll
      for(int nt=0;nt<16;nt++){
        f32x4 acc = {0.f,0.f,0.f,0.f};
        #pragma unroll
        for(int kk=0;kk<8;kk++)
          acc = __builtin_amdgcn_mfma_f32_16x16x32_f16(wl[(nt*8+kk)*64+lane], bf[kk], acc, 0,0,0);
        #pragma unroll
        for(int r=0;r<4;r++) nst[nt>>1][(nt&1)*4+r] = (f16)acc[r];
      }
    }
    __syncthreads();
  }

  // ---- phase 5: tangent final (mask4 in mbuf[0]) -> Wl, rows to LDS ----
  if (w>0){
    const char* mb = &mbuf[0][0];
    f32x4 acc = {0.f,0.f,0.f,0.f};
    #pragma unroll
    for(int kk=0;kk<8;kk++){
      f16x8 m8 = *(const f16x8*)(mb + moff(lane, kk));
      f16x8 bf = m8 * nst[kk];
      acc = __builtin_amdgcn_mfma_f32_16x16x32_f16(wlp[kk*64+lane], bf, acc, 0,0,0);
    }
    // D: col=lane&15=s, row=(lane>>4)*4+reg -> lanes 0..15 hold rows 0..3
    if (lane<16){
      outt[w-1][0][lane] = acc[0];
      outt[w-1][1][lane] = acc[1];
      outt[w-1][2][lane] = acc[2];
    }
  }
  __syncthreads();

  if (w==0 && lane<16){
    const int so = (sbase + lane)*3;
    out[so+0] = outt[1][2][lane] - outt[2][1][lane];  // da2/dx1 - da1/dx2
    out[so+1] = outt[2][0][lane] - outt[0][2][lane];  // da0/dx2 - da2/dx0
    out[so+2] = outt[0][1][lane] - outt[1][0][lane];  // da1/dx0 - da0/dx1
  }
}

extern "C" void kernel_launch(void* const* d_in, const int* in_sizes, int n_in,
                              void* d_out, int out_size, void* d_ws, size_t ws_size,
                              hipStream_t stream){
  const float* x  = (const float*)d_in[0];
  const float* W0 = (const float*)d_in[1];
  const float* b0 = (const float*)d_in[2];
  const float* Wh = (const float*)d_in[3];
  const float* bh = (const float*)d_in[4];
  const float* Wl = (const float*)d_in[5];
  // d_in[6] = bl: constant offset of a, curl kills it.
  prepack<<<1440, 256, 0, stream>>>(W0, b0, Wh, bh, Wl, (unsigned char*)d_ws);
  velcurl<<<4096, 256, 0, stream>>>(x, (const unsigned char*)d_ws, (float*)d_out);
}

// Round 6
// 536.110 us; speedup vs baseline: 1.3899x; 1.3899x over previous
//
#include <hip/hip_runtime.h>

typedef _Float16 f16;
typedef _Float16 f16x4 __attribute__((ext_vector_type(4)));
typedef _Float16 f16x8 __attribute__((ext_vector_type(8)));
typedef float    f32x4 __attribute__((ext_vector_type(4)));

// ws layout (bytes)
#define OFF_WHP   0u          // f16 [5][16nt][8kk][64lane][8e]   = 655360 B
#define OFF_WLP   655360u     // f16 [8kk][64lane][8e]            = 8192 B
#define OFF_W0P   663552u     // f32 [8kk][64lane][8e][4i]        = 65536 B
#define OFF_B0P   729088u     // f32 [8kk][64lane][8e]            = 16384 B
#define OFF_GP    745472u     // f32 [3j][8kk][64lane][8e]        = 49152 B
#define OFF_BHP   794624u     // f32 [5l][16nt][64lane][4r]       = 81920 B

// k-slot map: slot (kk, lane-group g, elem e) -> k = (2kk+(e>>2))*16+4g+(e&3).
// Applied identically to A (weights, prepacked) and B (activations), so the
// MFMA D-output (n = nt*16+4g+r) lands exactly in next layer's B-slot
// (kk'=nt>>1, e'=(nt&1)*4+r): lane-local layer transitions.
__device__ __forceinline__ int phi(int kk, int g, int e){
  return (kk*2 + (e>>2))*16 + g*4 + (e&3);
}

__device__ __forceinline__ float tanh_fast(float z){
  float e = __builtin_amdgcn_exp2f(z * 2.885390081777927f);
  return 1.f - 2.f*__builtin_amdgcn_rcpf(e + 1.f);
}

__global__ void prepack(const float* __restrict__ W0, const float* __restrict__ b0,
                        const float* __restrict__ Wh, const float* __restrict__ bh,
                        const float* __restrict__ Wl, unsigned char* __restrict__ ws){
  int tid = blockIdx.x*256 + threadIdx.x;
  f16*   whp = (f16*)(ws + OFF_WHP);
  f16*   wlp = (f16*)(ws + OFF_WLP);
  float* w0p = (float*)(ws + OFF_W0P);
  float* b0p = (float*)(ws + OFF_B0P);
  float* gp  = (float*)(ws + OFF_GP);
  float* bhp = (float*)(ws + OFF_BHP);
  if (tid < 327680){                      // Wh fragments, f16
    int e=tid&7, lane=(tid>>3)&63, kk=(tid>>9)&7, nt=(tid>>12)&15, l=tid>>16;
    int k = phi(kk, lane>>4, e);
    int n = nt*16 + (lane&15);
    whp[tid] = (f16)Wh[(l*256 + k)*256 + n];
  } else if (tid < 331776){               // Wl fragments (N padded 3->16), f16
    int t = tid - 327680;
    int e=t&7, lane=(t>>3)&63, kk=t>>9;
    int k = phi(kk, lane>>4, e);
    int n = lane&15;
    wlp[t] = (n<3) ? (f16)Wl[k*3+n] : (f16)0.f;
  } else if (tid < 335872){               // W0 columns + b0 in slot order, f32
    int t = tid - 331776;
    int e=t&7, lane=(t>>3)&63, kk=t>>9;
    int k = phi(kk, lane>>4, e);
    #pragma unroll
    for(int i=0;i<4;i++) w0p[t*4+i] = W0[i*256+k];
    b0p[t] = b0[k];
  } else if (tid < 348160){               // g_j = W0[j,:] @ Wh[0], slot order, f32
    int t = tid - 335872;
    int e=t&7, lane=(t>>3)&63, kk=(t>>9)&7, j=t>>12;
    int k = phi(kk, lane>>4, e);
    float acc = 0.f;
    for(int k0=0;k0<256;k0++) acc = fmaf(W0[j*256+k0], Wh[k0*256+k], acc);
    gp[t] = acc;
  } else if (tid < 368640){               // bh in D-layout order, f32
    int t = tid - 348160;
    int r=t&3, lane=(t>>2)&63, nt=(t>>8)&15, l=t>>12;
    bhp[t] = bh[l*256 + nt*16 + (lane>>4)*4 + r];
  }
}

// Lane-local mask layout: writer lane (s,g) of wave0 produces exactly the mask
// set reader lane (s,g) of waves 1..3 needs (n = nt*16+4g+r both sides).
// Masks at [lane][chunk kk] f16x8, chunk XOR-swizzled; one ds_read_b128 per kk.
__device__ __forceinline__ int moff(int lane, int kk){
  return lane*128 + ((kk ^ (lane & 7)) << 4);
}

// Comp-per-wave decomposition: wave 0 = primal chain (publishes tanh' masks),
// waves 1..3 = one tangent chain each. Per-wave demand ~124 VGPR + ~16 AGPR.
// R6: min-waves/EU = 3 (budget 512/3 = 170 >= 140 demand). R5's (256,4) capped
// the unified file at 128/wave -> allocator split 64V + AGPR and spilled
// (WRITE_SIZE 768B -> 258MB, dur 357 -> 685us). 4 blocks/CU is infeasible
// without a state redesign; 3 is the no-spill occupancy frontier.
__global__ __launch_bounds__(256, 3) void velcurl(
    const float* __restrict__ x, const unsigned char* __restrict__ ws,
    float* __restrict__ out){
  __shared__ __align__(16) char mbuf[2][8192];   // masks, double-buffered
  __shared__ float outt[3][3][16];               // [j][n][s] final Jacobian rows

  const int lane  = threadIdx.x & 63;
  const int w     = threadIdx.x >> 6;   // 0 = primal, 1..3 = tangent j=w-1
  const int s     = lane & 15;          // sample column
  const int sbase = blockIdx.x << 4;    // 16 samples per block

  const f16x8* __restrict__ whp = (const f16x8*)(ws + OFF_WHP);
  const f16x8* __restrict__ wlp = (const f16x8*)(ws + OFF_WLP);
  const f32x4* __restrict__ w0p = (const f32x4*)(ws + OFF_W0P);
  const float* __restrict__ b0p = (const float*)(ws + OFF_B0P);
  const float* __restrict__ gp  = (const float*)(ws + OFF_GP);
  const f32x4* __restrict__ bhp = (const f32x4*)(ws + OFF_BHP);

  f16x8 st[8];    // primal: current h frags (B-slot order)
  f16x8 nst[8];   // next-state (primal h / unmasked tangent preact)

  // ---- phase 0: primal layer0 + Wh0, masks0 -> mbuf[0] ----
  if (w==0){
    const f32x4 xv = ((const f32x4*)x)[sbase + s];
    #pragma unroll
    for(int kk=0;kk<8;kk++){
      f16x8 v;
      #pragma unroll
      for(int e=0;e<8;e++){
        f32x4 wv = w0p[(kk*64+lane)*8+e];
        float b  = b0p[(kk*64+lane)*8+e];
        float h = fmaf(xv[3],wv[3], fmaf(xv[2],wv[2], fmaf(xv[1],wv[1], fmaf(xv[0],wv[0], b))));
        v[e] = (f16)h;
      }
      st[kk] = v;
    }
    f16x8 mc;
    #pragma unroll
    for(int nt=0;nt<16;nt++){
      f32x4 acc = {0.f,0.f,0.f,0.f};
      #pragma unroll
      for(int kk=0;kk<8;kk++)
        acc = __builtin_amdgcn_mfma_f32_16x16x32_f16(whp[(nt*8+kk)*64+lane], st[kk], acc, 0,0,0);
      f32x4 bv = bhp[nt*64+lane];
      #pragma unroll
      for(int r=0;r<4;r++){
        float h = tanh_fast(acc[r]+bv[r]);
        nst[nt>>1][(nt&1)*4+r] = (f16)h;
        mc[(nt&1)*4+r] = (f16)(1.f - h*h);
      }
      if (nt&1) *(f16x8*)(&mbuf[0][0] + moff(lane, nt>>1)) = mc;
    }
    #pragma unroll
    for(int kk=0;kk<8;kk++) st[kk]=nst[kk];
  }
  __syncthreads();

  // ---- phases 1..4: primal layer p || tangent layer p (uses masks p-1) ----
  #pragma unroll 1
  for(int p=1;p<5;p++){
    const f16x8* wl = whp + p*8192;
    if (w==0){
      const f32x4* bp = bhp + p*1024;
      char* mb = &mbuf[p&1][0];
      f16x8 mc;
      #pragma unroll
      for(int nt=0;nt<16;nt++){
        f32x4 acc = {0.f,0.f,0.f,0.f};
        #pragma unroll
        for(int kk=0;kk<8;kk++)
          acc = __builtin_amdgcn_mfma_f32_16x16x32_f16(wl[(nt*8+kk)*64+lane], st[kk], acc, 0,0,0);
        f32x4 bv = bp[nt*64+lane];
        #pragma unroll
        for(int r=0;r<4;r++){
          float h = tanh_fast(acc[r]+bv[r]);
          nst[nt>>1][(nt&1)*4+r] = (f16)h;
          mc[(nt&1)*4+r] = (f16)(1.f - h*h);
        }
        if (nt&1) *(f16x8*)(mb + moff(lane, nt>>1)) = mc;
      }
      #pragma unroll
      for(int kk=0;kk<8;kk++) st[kk]=nst[kk];
    } else {
      const char* mb = &mbuf[(p-1)&1][0];
      f16x8 bf[8];
      if (p==1){
        const int j = w-1;
        #pragma unroll
        for(int kk=0;kk<8;kk++){
          f16x8 m8 = *(const f16x8*)(mb + moff(lane, kk));
          f16x8 v;
          #pragma unroll
          for(int e=0;e<8;e++)
            v[e] = (f16)((float)m8[e] * gp[((j*8+kk)*64+lane)*8 + e]);
          bf[kk] = v;
        }
      } else {
        #pragma unroll
        for(int kk=0;kk<8;kk++){
          f16x8 m8 = *(const f16x8*)(mb + moff(lane, kk));
          bf[kk] = m8 * nst[kk];
        }
      }
      #pragma unroll
      for(int nt=0;nt<16;nt++){
        f32x4 acc = {0.f,0.f,0.f,0.f};
        #pragma unroll
        for(int kk=0;kk<8;kk++)
          acc = __builtin_amdgcn_mfma_f32_16x16x32_f16(wl[(nt*8+kk)*64+lane], bf[kk], acc, 0,0,0);
        #pragma unroll
        for(int r=0;r<4;r++) nst[nt>>1][(nt&1)*4+r] = (f16)acc[r];
      }
    }
    __syncthreads();
  }

  // ---- phase 5: tangent final (mask4 in mbuf[0]) -> Wl, rows to LDS ----
  if (w>0){
    const char* mb = &mbuf[0][0];
    f32x4 acc = {0.f,0.f,0.f,0.f};
    #pragma unroll
    for(int kk=0;kk<8;kk++){
      f16x8 m8 = *(const f16x8*)(mb + moff(lane, kk));
      f16x8 bf = m8 * nst[kk];
      acc = __builtin_amdgcn_mfma_f32_16x16x32_f16(wlp[kk*64+lane], bf, acc, 0,0,0);
    }
    // D: col=lane&15=s, row=(lane>>4)*4+reg -> lanes 0..15 hold rows 0..3
    if (lane<16){
      outt[w-1][0][lane] = acc[0];
      outt[w-1][1][lane] = acc[1];
      outt[w-1][2][lane] = acc[2];
    }
  }
  __syncthreads();

  if (w==0 && lane<16){
    const int so = (sbase + lane)*3;
    out[so+0] = outt[1][2][lane] - outt[2][1][lane];  // da2/dx1 - da1/dx2
    out[so+1] = outt[2][0][lane] - outt[0][2][lane];  // da0/dx2 - da2/dx0
    out[so+2] = outt[0][1][lane] - outt[1][0][lane];  // da1/dx0 - da0/dx1
  }
}

extern "C" void kernel_launch(void* const* d_in, const int* in_sizes, int n_in,
                              void* d_out, int out_size, void* d_ws, size_t ws_size,
                              hipStream_t stream){
  const float* x  = (const float*)d_in[0];
  const float* W0 = (const float*)d_in[1];
  const float* b0 = (const float*)d_in[2];
  const float* Wh = (const float*)d_in[3];
  const float* bh = (const float*)d_in[4];
  const float* Wl = (const float*)d_in[5];
  // d_in[6] = bl: constant offset of a, curl kills it.
  prepack<<<1440, 256, 0, stream>>>(W0, b0, Wh, bh, Wl, (unsigned char*)d_ws);
  velcurl<<<4096, 256, 0, stream>>>(x, (const unsigned char*)d_ws, (float*)d_out);
}

// Round 9
// 381.254 us; speedup vs baseline: 1.9544x; 1.4062x over previous
//
#include <hip/hip_runtime.h>

typedef _Float16 f16;
typedef _Float16 f16x4 __attribute__((ext_vector_type(4)));
typedef _Float16 f16x8 __attribute__((ext_vector_type(8)));
typedef float    f32x4 __attribute__((ext_vector_type(4)));

// ws layout (bytes)
#define OFF_WHP   0u          // f16 [5][16nt][8kk][64lane][8e]   = 655360 B
#define OFF_WLP   655360u     // f16 [8kk][64lane][8e]            = 8192 B
#define OFF_W0P   663552u     // f32 [8kk][64lane][8e][4i]        = 65536 B
#define OFF_B0P   729088u     // f32 [8kk][64lane][8e]            = 16384 B
#define OFF_GP    745472u     // f32 [3j][8kk][64lane][8e]        = 49152 B
#define OFF_BHP   794624u     // f32 [5l][16nt][64lane][4r]       = 81920 B

// k-slot map: slot (kk, lane-group g, elem e) -> k = (2kk+(e>>2))*16+4g+(e&3).
// Applied identically to A (weights, prepacked) and B (activations), so the
// MFMA D-output (n = nt*16+4g+r) lands exactly in next layer's B-slot
// (kk'=nt>>1, e'=(nt&1)*4+r): lane-local layer transitions.
__device__ __forceinline__ int phi(int kk, int g, int e){
  return (kk*2 + (e>>2))*16 + g*4 + (e&3);
}

__device__ __forceinline__ float tanh_fast(float z){
  float e = __builtin_amdgcn_exp2f(z * 2.885390081777927f);
  return 1.f - 2.f*__builtin_amdgcn_rcpf(e + 1.f);
}

__global__ void prepack(const float* __restrict__ W0, const float* __restrict__ b0,
                        const float* __restrict__ Wh, const float* __restrict__ bh,
                        const float* __restrict__ Wl, unsigned char* __restrict__ ws){
  int tid = blockIdx.x*256 + threadIdx.x;
  f16*   whp = (f16*)(ws + OFF_WHP);
  f16*   wlp = (f16*)(ws + OFF_WLP);
  float* w0p = (float*)(ws + OFF_W0P);
  float* b0p = (float*)(ws + OFF_B0P);
  float* gp  = (float*)(ws + OFF_GP);
  float* bhp = (float*)(ws + OFF_BHP);
  if (tid < 327680){                      // Wh fragments, f16
    int e=tid&7, lane=(tid>>3)&63, kk=(tid>>9)&7, nt=(tid>>12)&15, l=tid>>16;
    int k = phi(kk, lane>>4, e);
    int n = nt*16 + (lane&15);
    whp[tid] = (f16)Wh[(l*256 + k)*256 + n];
  } else if (tid < 331776){               // Wl fragments (N padded 3->16), f16
    int t = tid - 327680;
    int e=t&7, lane=(t>>3)&63, kk=t>>9;
    int k = phi(kk, lane>>4, e);
    int n = lane&15;
    wlp[t] = (n<3) ? (f16)Wl[k*3+n] : (f16)0.f;
  } else if (tid < 335872){               // W0 columns + b0 in slot order, f32
    int t = tid - 331776;
    int e=t&7, lane=(t>>3)&63, kk=t>>9;
    int k = phi(kk, lane>>4, e);
    #pragma unroll
    for(int i=0;i<4;i++) w0p[t*4+i] = W0[i*256+k];
    b0p[t] = b0[k];
  } else if (tid < 348160){               // g_j = W0[j,:] @ Wh[0], slot order, f32
    int t = tid - 335872;
    int e=t&7, lane=(t>>3)&63, kk=(t>>9)&7, j=t>>12;
    int k = phi(kk, lane>>4, e);
    float acc = 0.f;
    for(int k0=0;k0<256;k0++) acc = fmaf(W0[j*256+k0], Wh[k0*256+k], acc);
    gp[t] = acc;
  } else if (tid < 368640){               // bh in D-layout order, f32
    int t = tid - 348160;
    int r=t&3, lane=(t>>2)&63, nt=(t>>8)&15, l=t>>12;
    bhp[t] = bh[l*256 + nt*16 + (lane>>4)*4 + r];
  }
}

// Lane-local mask layout: writer lane (s,g) of wave0 produces exactly the mask
// set reader lane (s,g) of waves 1..3 needs (n = nt*16+4g+r both sides).
// Masks at [lane][chunk kk] f16x8, chunk XOR-swizzled; one ds_read_b128 per kk.
__device__ __forceinline__ int moff(int lane, int kk){
  return lane*128 + ((kk ^ (lane & 7)) << 4);
}

// R7: 2 sample-tiles per wave (32 samples/block, 2048 blocks). R4 was bound by
// the L2 weight stream (every wave re-reads the 128KB layer per phase: ~9 GB
// total = ~25 TB/s ~ 72% of L2 ceiling, MfmaUtil 18%). Each weight fragment
// now feeds 2 MFMAs (one per tile): halves L2 traffic, doubles acc-chain ILP.
// launch_bounds (256,2): R5/R6 proved smaller budgets force AGPR-copies/spill
// (dur 685/497 vs 357); this structure needs the full 256-reg file.
__global__ __launch_bounds__(256, 2) void velcurl(
    const float* __restrict__ x, const unsigned char* __restrict__ ws,
    float* __restrict__ out){
  __shared__ __align__(16) char mbuf[2][2][8192];  // [dbuf][tile] masks
  __shared__ float outt[2][3][3][16];              // [tile][j][n][s] Jacobian rows

  const int lane  = threadIdx.x & 63;
  const int w     = threadIdx.x >> 6;   // 0 = primal, 1..3 = tangent j=w-1
  const int s     = lane & 15;          // sample column
  const int sbase = blockIdx.x << 5;    // 32 samples per block

  const f16x8* __restrict__ whp = (const f16x8*)(ws + OFF_WHP);
  const f16x8* __restrict__ wlp = (const f16x8*)(ws + OFF_WLP);
  const f32x4* __restrict__ w0p = (const f32x4*)(ws + OFF_W0P);
  const float* __restrict__ b0p = (const float*)(ws + OFF_B0P);
  const float* __restrict__ gp  = (const float*)(ws + OFF_GP);
  const f32x4* __restrict__ bhp = (const f32x4*)(ws + OFF_BHP);

  f16x8 st[2][8];    // primal h frags / tangent bf (B-slot order), per tile
  f16x8 nst[2][8];   // next-state (primal h / unmasked tangent preact)

  // ---- phase 0: primal layer0 + Wh0, masks0 -> mbuf[0] ----
  if (w==0){
    const f32x4 xv0 = ((const f32x4*)x)[sbase + s];
    const f32x4 xv1 = ((const f32x4*)x)[sbase + 16 + s];
    #pragma unroll
    for(int kk=0;kk<8;kk++){
      f16x8 v0, v1;
      #pragma unroll
      for(int e=0;e<8;e++){
        f32x4 wv = w0p[(kk*64+lane)*8+e];
        float b  = b0p[(kk*64+lane)*8+e];
        v0[e] = (f16)fmaf(xv0[3],wv[3], fmaf(xv0[2],wv[2], fmaf(xv0[1],wv[1], fmaf(xv0[0],wv[0], b))));
        v1[e] = (f16)fmaf(xv1[3],wv[3], fmaf(xv1[2],wv[2], fmaf(xv1[1],wv[1], fmaf(xv1[0],wv[0], b))));
      }
      st[0][kk] = v0; st[1][kk] = v1;
    }
    f16x8 mc0, mc1;
    #pragma unroll
    for(int nt=0;nt<16;nt++){
      f32x4 a0 = {0.f,0.f,0.f,0.f}, a1 = {0.f,0.f,0.f,0.f};
      #pragma unroll
      for(int kk=0;kk<8;kk++){
        f16x8 frag = whp[(nt*8+kk)*64+lane];
        a0 = __builtin_amdgcn_mfma_f32_16x16x32_f16(frag, st[0][kk], a0, 0,0,0);
        a1 = __builtin_amdgcn_mfma_f32_16x16x32_f16(frag, st[1][kk], a1, 0,0,0);
      }
      f32x4 bv = bhp[nt*64+lane];   // bias: sample-independent
      #pragma unroll
      for(int r=0;r<4;r++){
        float h0 = tanh_fast(a0[r]+bv[r]);
        float h1 = tanh_fast(a1[r]+bv[r]);
        nst[0][nt>>1][(nt&1)*4+r] = (f16)h0;
        nst[1][nt>>1][(nt&1)*4+r] = (f16)h1;
        mc0[(nt&1)*4+r] = (f16)(1.f - h0*h0);
        mc1[(nt&1)*4+r] = (f16)(1.f - h1*h1);
      }
      if (nt&1){
        *(f16x8*)(&mbuf[0][0][0] + moff(lane, nt>>1)) = mc0;
        *(f16x8*)(&mbuf[0][1][0] + moff(lane, nt>>1)) = mc1;
      }
    }
    #pragma unroll
    for(int kk=0;kk<8;kk++){ st[0][kk]=nst[0][kk]; st[1][kk]=nst[1][kk]; }
  }
  __syncthreads();

  // ---- phases 1..4: primal layer p || tangent layer p (uses masks p-1) ----
  #pragma unroll 1
  for(int p=1;p<5;p++){
    const f16x8* wl = whp + p*8192;
    if (w==0){
      const f32x4* bp = bhp + p*1024;
      f16x8 mc0, mc1;
      #pragma unroll
      for(int nt=0;nt<16;nt++){
        f32x4 a0 = {0.f,0.f,0.f,0.f}, a1 = {0.f,0.f,0.f,0.f};
        #pragma unroll
        for(int kk=0;kk<8;kk++){
          f16x8 frag = wl[(nt*8+kk)*64+lane];
          a0 = __builtin_amdgcn_mfma_f32_16x16x32_f16(frag, st[0][kk], a0, 0,0,0);
          a1 = __builtin_amdgcn_mfma_f32_16x16x32_f16(frag, st[1][kk], a1, 0,0,0);
        }
        f32x4 bv = bp[nt*64+lane];
        #pragma unroll
        for(int r=0;r<4;r++){
          float h0 = tanh_fast(a0[r]+bv[r]);
          float h1 = tanh_fast(a1[r]+bv[r]);
          nst[0][nt>>1][(nt&1)*4+r] = (f16)h0;
          nst[1][nt>>1][(nt&1)*4+r] = (f16)h1;
          mc0[(nt&1)*4+r] = (f16)(1.f - h0*h0);
          mc1[(nt&1)*4+r] = (f16)(1.f - h1*h1);
        }
        if (nt&1){
          *(f16x8*)(&mbuf[p&1][0][0] + moff(lane, nt>>1)) = mc0;
          *(f16x8*)(&mbuf[p&1][1][0] + moff(lane, nt>>1)) = mc1;
        }
      }
      #pragma unroll
      for(int kk=0;kk<8;kk++){ st[0][kk]=nst[0][kk]; st[1][kk]=nst[1][kk]; }
    } else {
      const char* mb0 = &mbuf[(p-1)&1][0][0];
      const char* mb1 = &mbuf[(p-1)&1][1][0];
      if (p==1){
        const int j = w-1;
        #pragma unroll
        for(int kk=0;kk<8;kk++){
          f16x8 m80 = *(const f16x8*)(mb0 + moff(lane, kk));
          f16x8 m81 = *(const f16x8*)(mb1 + moff(lane, kk));
          f16x8 v0, v1;
          #pragma unroll
          for(int e=0;e<8;e++){
            float gv = gp[((j*8+kk)*64+lane)*8 + e];   // sample-independent
            v0[e] = (f16)((float)m80[e] * gv);
            v1[e] = (f16)((float)m81[e] * gv);
          }
          st[0][kk] = v0; st[1][kk] = v1;
        }
      } else {
        #pragma unroll
        for(int kk=0;kk<8;kk++){
          f16x8 m80 = *(const f16x8*)(mb0 + moff(lane, kk));
          f16x8 m81 = *(const f16x8*)(mb1 + moff(lane, kk));
          st[0][kk] = m80 * nst[0][kk];
          st[1][kk] = m81 * nst[1][kk];
        }
      }
      #pragma unroll
      for(int nt=0;nt<16;nt++){
        f32x4 a0 = {0.f,0.f,0.f,0.f}, a1 = {0.f,0.f,0.f,0.f};
        #pragma unroll
        for(int kk=0;kk<8;kk++){
          f16x8 frag = wl[(nt*8+kk)*64+lane];
          a0 = __builtin_amdgcn_mfma_f32_16x16x32_f16(frag, st[0][kk], a0, 0,0,0);
          a1 = __builtin_amdgcn_mfma_f32_16x16x32_f16(frag, st[1][kk], a1, 0,0,0);
        }
        #pragma unroll
        for(int r=0;r<4;r++){
          nst[0][nt>>1][(nt&1)*4+r] = (f16)a0[r];
          nst[1][nt>>1][(nt&1)*4+r] = (f16)a1[r];
        }
      }
    }
    __syncthreads();
  }

  // ---- phase 5: tangent final (mask4 in mbuf[0]) -> Wl, rows to LDS ----
  if (w>0){
    const char* mb0 = &mbuf[0][0][0];
    const char* mb1 = &mbuf[0][1][0];
    f32x4 a0 = {0.f,0.f,0.f,0.f}, a1 = {0.f,0.f,0.f,0.f};
    #pragma unroll
    for(int kk=0;kk<8;kk++){
      f16x8 frag = wlp[kk*64+lane];
      f16x8 m80 = *(const f16x8*)(mb0 + moff(lane, kk));
      f16x8 m81 = *(const f16x8*)(mb1 + moff(lane, kk));
      a0 = __builtin_amdgcn_mfma_f32_16x16x32_f16(frag, m80 * nst[0][kk], a0, 0,0,0);
      a1 = __builtin_amdgcn_mfma_f32_16x16x32_f16(frag, m81 * nst[1][kk], a1, 0,0,0);
    }
    // D: col=lane&15=s, row=(lane>>4)*4+reg -> lanes 0..15 hold rows 0..3
    if (lane<16){
      outt[0][w-1][0][lane] = a0[0];
      outt[0][w-1][1][lane] = a0[1];
      outt[0][w-1][2][lane] = a0[2];
      outt[1][w-1][0][lane] = a1[0];
      outt[1][w-1][1][lane] = a1[1];
      outt[1][w-1][2][lane] = a1[2];
    }
  }
  __syncthreads();

  if (w==0 && lane<32){
    const int t = lane>>4, ss = lane&15;
    const int so = (sbase + lane)*3;
    out[so+0] = outt[t][1][2][ss] - outt[t][2][1][ss];  // da2/dx1 - da1/dx2
    out[so+1] = outt[t][2][0][ss] - outt[t][0][2][ss];  // da0/dx2 - da2/dx0
    out[so+2] = outt[t][0][1][ss] - outt[t][1][0][ss];  // da1/dx0 - da0/dx1
  }
}

extern "C" void kernel_launch(void* const* d_in, const int* in_sizes, int n_in,
                              void* d_out, int out_size, void* d_ws, size_t ws_size,
                              hipStream_t stream){
  const float* x  = (const float*)d_in[0];
  const float* W0 = (const float*)d_in[1];
  const float* b0 = (const float*)d_in[2];
  const float* Wh = (const float*)d_in[3];
  const float* bh = (const float*)d_in[4];
  const float* Wl = (const float*)d_in[5];
  // d_in[6] = bl: constant offset of a, curl kills it.
  prepack<<<1440, 256, 0, stream>>>(W0, b0, Wh, bh, Wl, (unsigned char*)d_ws);
  velcurl<<<2048, 256, 0, stream>>>(x, (const unsigned char*)d_ws, (float*)d_out);
}